// Round 3
// baseline (634.369 us; speedup 1.0000x reference)
//
#include <hip/hip_runtime.h>
#include <hip/hip_bf16.h>
#include <math.h>

// Problem constants (from reference): B=2,S=2048,D=1024,F=4096,E=8,K=2
#define Dv 1024
#define Fv 4096
#define Ev 8
#define Tt 4096
#define CAP 2048
#define NROW 8192   // max total kept slots = 2*Tt
#define RPAD 128    // staging over-read pad rows

typedef unsigned int u32;
typedef __bf16 bf16x8 __attribute__((ext_vector_type(8)));
typedef float f32x4 __attribute__((ext_vector_type(4)));

__device__ __forceinline__ unsigned short f2bf(float f) {
  u32 u = __float_as_uint(f);
  u32 r = (u + 0x7fffu + ((u >> 16) & 1u)) >> 16;
  return (unsigned short)r;
}

__device__ __forceinline__ void gload_lds16(const void* g, void* l) {
  __builtin_amdgcn_global_load_lds(
      (const __attribute__((address_space(1))) u32*)g,
      (__attribute__((address_space(3))) u32*)l, 16, 0, 0);
}

// ---------- transpose fp32 [R,C] -> bf16 [C,R], per expert (blockIdx.z) ----------
__global__ void __launch_bounds__(256)
transpose_bf16_kernel(const float* __restrict__ src, unsigned short* __restrict__ dst,
                      int R, int Cc) {
  __shared__ float tile[64][65];
  int e = blockIdx.z;
  src += (size_t)e * R * Cc;
  dst += (size_t)e * R * Cc;
  int c0 = blockIdx.x * 64, r0 = blockIdx.y * 64;
  int tc = threadIdx.x & 63, tr = threadIdx.x >> 6;  // 64 x 4
#pragma unroll
  for (int i = tr; i < 64; i += 4)
    tile[i][tc] = src[(size_t)(r0 + i) * Cc + (c0 + tc)];
  __syncthreads();
  int rp = (threadIdx.x & 31) * 2, co = threadIdx.x >> 5;  // 32 x 8
#pragma unroll
  for (int k = 0; k < 8; ++k) {
    int c = co + 8 * k;
    ushort2 v;
    v.x = f2bf(tile[rp][c]);
    v.y = f2bf(tile[rp + 1][c]);
    *(ushort2*)&dst[(size_t)(c0 + c) * R + (r0 + rp)] = v;
  }
}

// ---------- gating: one wave per token, fp32 ----------
__global__ void __launch_bounds__(256)
gating_kernel(const float* __restrict__ x, const float* __restrict__ Wg,
              int* __restrict__ idx1, int* __restrict__ idx2,
              float* __restrict__ w1, float* __restrict__ w2) {
  int t = blockIdx.x * 4 + (threadIdx.x >> 6);
  int lane = threadIdx.x & 63;
  const float* xr = x + (size_t)t * Dv;
  float acc[Ev];
#pragma unroll
  for (int e = 0; e < Ev; ++e) acc[e] = 0.f;
#pragma unroll
  for (int j = 0; j < 4; ++j) {
    int dbase = (lane + 64 * j) * 4;
    float4 xv = *(const float4*)(xr + dbase);
    const float* wr = Wg + (size_t)dbase * Ev;
#pragma unroll
    for (int u = 0; u < 4; ++u) {
      float xd = (&xv.x)[u];
#pragma unroll
      for (int e = 0; e < Ev; ++e) acc[e] += xd * wr[u * Ev + e];
    }
  }
#pragma unroll
  for (int off = 32; off > 0; off >>= 1) {
#pragma unroll
    for (int e = 0; e < Ev; ++e) acc[e] += __shfl_xor(acc[e], off, 64);
  }
  if (lane == 0) {
    float mx = acc[0]; int i1 = 0;
#pragma unroll
    for (int e = 1; e < Ev; ++e) { if (acc[e] > mx) { mx = acc[e]; i1 = e; } }
    float ge[Ev]; float se = 0.f;
#pragma unroll
    for (int e = 0; e < Ev; ++e) { ge[e] = expf(acc[e] - mx); se += ge[e]; }
    float mx2 = -INFINITY; int i2 = 0; bool have = false;
#pragma unroll
    for (int e = 0; e < Ev; ++e) {
      if (e == i1) continue;
      if (!have || acc[e] > mx2) { mx2 = acc[e]; i2 = e; have = true; }
    }
    float g1 = 0.f, g2 = 0.f;
#pragma unroll
    for (int e = 0; e < Ev; ++e) { if (e == i1) g1 = ge[e]; if (e == i2) g2 = ge[e]; }
    g1 /= se; g2 /= se;
    float denom = g1 + g2 + 1e-9f;
    idx1[t] = i1; idx2[t] = i2;
    w1[t] = g1 / denom; w2[t] = g2 / denom;
  }
}

// ---------- GShard slot assignment scan (single block) ----------
// Outputs COMPACT row indices: ci = base[e] + pos (or -1 if dropped),
// plus n_e[e] and base[e] (exclusive prefix of n_e).
__global__ void __launch_bounds__(256)
scan_kernel(const int* __restrict__ gidx1, const int* __restrict__ gidx2,
            const float* __restrict__ gw1, const float* __restrict__ gw2,
            int* __restrict__ ci1, int* __restrict__ ci2,
            float* __restrict__ w1k, float* __restrict__ w2k,
            int* __restrict__ n_e, int* __restrict__ base_e) {
  __shared__ short s1[Tt], s2[Tt];
  __shared__ int c1[256][Ev], c2[256][Ev];
  __shared__ int tot1[Ev], tot2[Ev], sne[Ev], sbase[Ev];
  int tid = threadIdx.x;
  for (int i = tid; i < Tt; i += 256) { s1[i] = (short)gidx1[i]; s2[i] = (short)gidx2[i]; }
  __syncthreads();
  int base = tid * 16;
  {
    int l1[Ev], l2[Ev];
#pragma unroll
    for (int e = 0; e < Ev; ++e) { l1[e] = 0; l2[e] = 0; }
    for (int j = 0; j < 16; ++j) {
      int a = s1[base + j], b = s2[base + j];
#pragma unroll
      for (int e = 0; e < Ev; ++e) { l1[e] += (a == e); l2[e] += (b == e); }
    }
#pragma unroll
    for (int e = 0; e < Ev; ++e) { c1[tid][e] = l1[e]; c2[tid][e] = l2[e]; }
  }
  __syncthreads();
  if (tid < 2 * Ev) {
    int e = tid & 7;
    int* col = (tid < Ev) ? &c1[0][e] : &c2[0][e];
    int run = 0;
    for (int c = 0; c < 256; ++c) { int v = col[(size_t)c * Ev]; col[(size_t)c * Ev] = run; run += v; }
    if (tid < Ev) tot1[e] = run; else tot2[e] = run;
  }
  __syncthreads();
  if (tid == 0) {
    int b = 0;
#pragma unroll
    for (int e = 0; e < Ev; ++e) {
      int ne = tot1[e] + tot2[e];
      ne = ne < CAP ? ne : CAP;
      sne[e] = ne; sbase[e] = b;
      n_e[e] = ne; base_e[e] = b;
      b += ne;
    }
  }
  __syncthreads();
  int r1[Ev], r2[Ev];
#pragma unroll
  for (int e = 0; e < Ev; ++e) { r1[e] = c1[tid][e]; r2[e] = c2[tid][e] + tot1[e]; }
  for (int j = 0; j < 16; ++j) {
    int tk = base + j;
    int e1 = s1[tk], e2 = s2[tk];
    int p1 = 0, p2 = 0;
#pragma unroll
    for (int e = 0; e < Ev; ++e) {
      if (e == e1) { p1 = r1[e]; r1[e]++; }
      if (e == e2) { p2 = r2[e]; r2[e]++; }
    }
    bool k1 = p1 < CAP, k2 = p2 < CAP;
    ci1[tk] = k1 ? (sbase[e1] + p1) : -1;
    ci2[tk] = k2 ? (sbase[e2] + p2) : -1;
    w1k[tk] = k1 ? gw1[tk] : 0.f;
    w2k[tk] = k2 ? gw2[tk] : 0.f;
  }
}

// ---------- dispatch: scatter token rows to compact slots (bf16) ----------
__global__ void __launch_bounds__(256)
dispatch_kernel(const float* __restrict__ x,
                const int* __restrict__ ci1, const int* __restrict__ ci2,
                unsigned short* __restrict__ Xe) {
  int t = blockIdx.x, tid = threadIdx.x;
  float4 xv = *(const float4*)(x + (size_t)t * Dv + tid * 4);
  ushort4 bv;
  bv.x = f2bf(xv.x); bv.y = f2bf(xv.y); bv.z = f2bf(xv.z); bv.w = f2bf(xv.w);
  int c1 = ci1[t], c2 = ci2[t];
  if (c1 >= 0) *(ushort4*)(Xe + (size_t)c1 * Dv + tid * 4) = bv;
  if (c2 >= 0) *(ushort4*)(Xe + (size_t)c2 * Dv + tid * 4) = bv;
}

// ---------- bf16 GEMM, BK=64, XOR-swizzled LDS, compact A rows ----------
// A: compact [NROW+RPAD, K] bf16 rows (row = base_e[e] + local)
// Bt: [E, N, K] bf16. grid: (x=expert, y=N/128, z=mtiles*SPLITS)
// MODE 0: Out = bf16 compact [NROW+RPAD, N], gelu(acc+bias)
// MODE 1: Out = fp32 [SPLITS][NROW, N], acc (+bias on split 0)
template <int MODE, int SPLITS>
__global__ void __launch_bounds__(256, 2)
gemm_kernel(const unsigned short* __restrict__ A,
            const unsigned short* __restrict__ Bt,
            const float* __restrict__ bias,
            void* __restrict__ Out,
            const int* __restrict__ n_e, const int* __restrict__ base_e,
            int N, int K) {
  int e = blockIdx.x;
  int zz = blockIdx.z;
  int split = zz % SPLITS, mt = zz / SPLITS;
  int m0 = mt * 128;
  int ne = n_e[e];
  if (m0 >= ne) return;
  int rbase = base_e[e];
  int n0 = blockIdx.y * 128;
  const int kchunk = K / SPLITS;
  A += ((size_t)(rbase + m0)) * K + (size_t)split * kchunk;
  Bt += (size_t)e * N * K + (size_t)n0 * K + (size_t)split * kchunk;
  bias += (size_t)e * N;

  __shared__ unsigned short As[128 * 64];
  __shared__ unsigned short Bs[128 * 64];
  int tid = threadIdx.x;
  int wave = tid >> 6, lane = tid & 63;
  int wm = (wave & 1) * 64, wn = (wave >> 1) * 64;
  int quad = lane >> 4, lr = lane & 15;
  int sw = lr & 7;
  f32x4 acc[4][4];
#pragma unroll
  for (int i = 0; i < 4; ++i)
#pragma unroll
    for (int j = 0; j < 4; ++j)
#pragma unroll
      for (int r = 0; r < 4; ++r) acc[i][j][r] = 0.f;

  int r_st = tid >> 3;   // 0..31
  int g_st = tid & 7;
  int gsrc = g_st ^ (r_st & 7);
  const unsigned short* gA = A + (size_t)r_st * K + gsrc * 8;
  const unsigned short* gB = Bt + (size_t)r_st * K + gsrc * 8;
  unsigned short* lA = &As[tid * 8];
  unsigned short* lB = &Bs[tid * 8];

  for (int k0 = 0; k0 < kchunk; k0 += 64) {
    __syncthreads();
#pragma unroll
    for (int s = 0; s < 4; ++s) {
      gload_lds16(gA + (size_t)(s * 32) * K + k0, lA + s * 2048);
      gload_lds16(gB + (size_t)(s * 32) * K + k0, lB + s * 2048);
    }
    __syncthreads();
#pragma unroll
    for (int h = 0; h < 2; ++h) {
      bf16x8 af[4], bfr[4];
#pragma unroll
      for (int mi = 0; mi < 4; ++mi) {
        int row = wm + mi * 16 + lr;
        int c = (h * 4 + quad) ^ sw;
        af[mi] = *(const bf16x8*)&As[row * 64 + c * 8];
      }
#pragma unroll
      for (int ni = 0; ni < 4; ++ni) {
        int row = wn + ni * 16 + lr;
        int c = (h * 4 + quad) ^ sw;
        bfr[ni] = *(const bf16x8*)&Bs[row * 64 + c * 8];
      }
#pragma unroll
      for (int mi = 0; mi < 4; ++mi)
#pragma unroll
        for (int ni = 0; ni < 4; ++ni)
          acc[mi][ni] = __builtin_amdgcn_mfma_f32_16x16x32_bf16(af[mi], bfr[ni], acc[mi][ni], 0, 0, 0);
    }
  }

#pragma unroll
  for (int ni = 0; ni < 4; ++ni) {
    int col = n0 + wn + ni * 16 + lr;
    float bv = (MODE == 0 || split == 0) ? bias[col] : 0.f;
#pragma unroll
    for (int mi = 0; mi < 4; ++mi) {
#pragma unroll
      for (int r = 0; r < 4; ++r) {
        int rowl = m0 + wm + mi * 16 + quad * 4 + r;
        if (rowl < ne) {
          size_t grow = (size_t)(rbase + rowl);
          float v = acc[mi][ni][r] + bv;
          if (MODE == 0) {
            v = 0.5f * v * (1.0f + erff(v * 0.70710678118654752f));
            ((unsigned short*)Out)[grow * N + col] = f2bf(v);
          } else {
            ((float*)Out)[((size_t)split * NROW + grow) * N + col] = v;
          }
        }
      }
    }
  }
}

// ---------- combine (sums split-K partials) ----------
__global__ void __launch_bounds__(256)
combine_kernel(const float* __restrict__ ye,   // [2][NROW][Dv]
               const int* __restrict__ ci1, const int* __restrict__ ci2,
               const float* __restrict__ w1k, const float* __restrict__ w2k,
               float* __restrict__ out) {
  int t = blockIdx.x, tid = threadIdx.x;
  int c1 = ci1[t], c2 = ci2[t];
  float a1 = w1k[t], a2 = w2k[t];
  const float* ye1 = ye + (size_t)NROW * Dv;
  float4 o = make_float4(0.f, 0.f, 0.f, 0.f);
  if (c1 >= 0) {
    float4 y0 = *(const float4*)(ye + (size_t)c1 * Dv + tid * 4);
    float4 y1 = *(const float4*)(ye1 + (size_t)c1 * Dv + tid * 4);
    o.x += a1 * (y0.x + y1.x); o.y += a1 * (y0.y + y1.y);
    o.z += a1 * (y0.z + y1.z); o.w += a1 * (y0.w + y1.w);
  }
  if (c2 >= 0) {
    float4 y0 = *(const float4*)(ye + (size_t)c2 * Dv + tid * 4);
    float4 y1 = *(const float4*)(ye1 + (size_t)c2 * Dv + tid * 4);
    o.x += a2 * (y0.x + y1.x); o.y += a2 * (y0.y + y1.y);
    o.z += a2 * (y0.z + y1.z); o.w += a2 * (y0.w + y1.w);
  }
  *(float4*)(out + (size_t)t * Dv + tid * 4) = o;
}

extern "C" void kernel_launch(void* const* d_in, const int* in_sizes, int n_in,
                              void* d_out, int out_size, void* d_ws, size_t ws_size,
                              hipStream_t stream) {
  const float* x  = (const float*)d_in[0];
  const float* Wg = (const float*)d_in[1];
  const float* W1 = (const float*)d_in[2];
  const float* b1 = (const float*)d_in[3];
  const float* W2 = (const float*)d_in[4];
  const float* b2 = (const float*)d_in[5];
  float* out = (float*)d_out;

  char* p = (char*)d_ws;
  size_t off = 0;
  auto alloc = [&](size_t bytes) {
    void* q = p + off;
    off += (bytes + 255) & ~(size_t)255;
    return q;
  };
  unsigned short* Wt1 = (unsigned short*)alloc((size_t)Ev * Fv * Dv * 2);       // 64MB (aliased by ye after fc1)
  unsigned short* Wt2 = (unsigned short*)alloc((size_t)Ev * Dv * Fv * 2);       // 64MB
  unsigned short* Xe  = (unsigned short*)alloc((size_t)(NROW + RPAD) * Dv * 2); // 17MB compact
  unsigned short* h   = (unsigned short*)alloc((size_t)(NROW + RPAD) * Fv * 2); // 68MB compact
  int*   idx1 = (int*)alloc(Tt * 4);
  int*   idx2 = (int*)alloc(Tt * 4);
  int*   ci1  = (int*)alloc(Tt * 4);
  int*   ci2  = (int*)alloc(Tt * 4);
  float* w1   = (float*)alloc(Tt * 4);
  float* w2   = (float*)alloc(Tt * 4);
  float* w1k  = (float*)alloc(Tt * 4);
  float* w2k  = (float*)alloc(Tt * 4);
  int*   n_e  = (int*)alloc(Ev * 4);
  int*   base = (int*)alloc(Ev * 4);
  float* ye   = (float*)Wt1;  // [2][NROW][Dv] fp32 = 64MB, aliases Wt1 (dead after fc1)

  // T1: W1[E,D,F] -> Wt1[E,F,D] bf16
  transpose_bf16_kernel<<<dim3(Fv / 64, Dv / 64, Ev), 256, 0, stream>>>(W1, Wt1, Dv, Fv);
  // gating
  gating_kernel<<<Tt / 4, 256, 0, stream>>>(x, Wg, idx1, idx2, w1, w2);
  // slot assignment -> compact indices
  scan_kernel<<<1, 256, 0, stream>>>(idx1, idx2, w1, w2, ci1, ci2, w1k, w2k, n_e, base);
  // dispatch to compact Xe
  dispatch_kernel<<<Tt, 256, 0, stream>>>(x, ci1, ci2, Xe);
  // fc1: h = gelu(Xe @ W1 + b1)  [N=F, K=D], grid x=expert for XCD locality
  gemm_kernel<0, 1><<<dim3(Ev, Fv / 128, CAP / 128), 256, 0, stream>>>(
      Xe, Wt1, b1, h, n_e, base, Fv, Dv);
  // T2: W2[E,F,D] -> Wt2[E,D,F] bf16 (after fc1 so Wt2 is LLC-hot for fc2)
  transpose_bf16_kernel<<<dim3(Dv / 64, Fv / 64, Ev), 256, 0, stream>>>(W2, Wt2, Fv, Dv);
  // fc2: ye = h @ W2 + b2, split-K x2  [N=D, K=F]
  gemm_kernel<1, 2><<<dim3(Ev, Dv / 128, (CAP / 128) * 2), 256, 0, stream>>>(
      h, Wt2, b2, ye, n_e, base, Dv, Fv);
  // combine
  combine_kernel<<<Tt, 256, 0, stream>>>(ye, ci1, ci2, w1k, w2k, out);
}

// Round 4
// 586.340 us; speedup vs baseline: 1.0819x; 1.0819x over previous
//
#include <hip/hip_runtime.h>
#include <hip/hip_bf16.h>
#include <math.h>

// Problem constants: B=2,S=2048,D=1024,F=4096,E=8,K=2
#define Dv 1024
#define Fv 4096
#define Ev 8
#define Tt 4096
#define CAP 2048
#define NROW 8192   // max total kept slots = 2*Tt
#define RPAD 128    // staging over-read pad rows

typedef unsigned int u32;
typedef __bf16 bf16x8 __attribute__((ext_vector_type(8)));
typedef float f32x4 __attribute__((ext_vector_type(4)));

__device__ __forceinline__ unsigned short f2bf(float f) {
  u32 u = __float_as_uint(f);
  u32 r = (u + 0x7fffu + ((u >> 16) & 1u)) >> 16;
  return (unsigned short)r;
}

__device__ __forceinline__ float bf2f(unsigned short s) {
  u32 u = ((u32)s) << 16;
  return __uint_as_float(u);
}

__device__ __forceinline__ void gload_lds16(const void* g, void* l) {
  __builtin_amdgcn_global_load_lds(
      (const __attribute__((address_space(1))) u32*)g,
      (__attribute__((address_space(3))) u32*)l, 16, 0, 0);
}

// ---------- fused pre-kernel: T1 | T2 | gating ----------
// blocks [0, 8192): transpose W1[E,D,F] -> Wt1[E,F,D]
// blocks [8192, 16384): transpose W2[E,F,D] -> Wt2[E,D,F]
// blocks [16384, 17408): gating (4 tokens/block)
__device__ __forceinline__ void do_transpose(const float* __restrict__ src,
                                             unsigned short* __restrict__ dst,
                                             int R, int Cc, int bid,
                                             float (*tile)[65]) {
  int ctiles = Cc >> 6;
  int rtiles = R >> 6;
  int cx = bid % ctiles;
  int ry = (bid / ctiles) % rtiles;
  int e = bid / (ctiles * rtiles);
  src += (size_t)e * R * Cc;
  dst += (size_t)e * R * Cc;
  int c0 = cx * 64, r0 = ry * 64;
  int tc = threadIdx.x & 63, tr = threadIdx.x >> 6;  // 64 x 4
#pragma unroll
  for (int i = tr; i < 64; i += 4)
    tile[i][tc] = src[(size_t)(r0 + i) * Cc + (c0 + tc)];
  __syncthreads();
  int rp = (threadIdx.x & 31) * 2, co = threadIdx.x >> 5;  // 32 x 8
#pragma unroll
  for (int k = 0; k < 8; ++k) {
    int c = co + 8 * k;
    ushort2 v;
    v.x = f2bf(tile[rp][c]);
    v.y = f2bf(tile[rp + 1][c]);
    *(ushort2*)&dst[(size_t)(c0 + c) * R + (r0 + rp)] = v;
  }
}

__global__ void __launch_bounds__(256)
pre_kernel(const float* __restrict__ W1, unsigned short* __restrict__ Wt1,
           const float* __restrict__ W2, unsigned short* __restrict__ Wt2,
           const float* __restrict__ x, const float* __restrict__ Wg,
           int* __restrict__ idx1, int* __restrict__ idx2,
           float* __restrict__ w1, float* __restrict__ w2) {
  __shared__ float tile[64][65];
  int bid = blockIdx.x;
  if (bid < 8192) {
    do_transpose(W1, Wt1, Dv, Fv, bid, tile);
    return;
  }
  if (bid < 16384) {
    do_transpose(W2, Wt2, Fv, Dv, bid - 8192, tile);
    return;
  }
  // gating: one wave per token
  int t = (bid - 16384) * 4 + (threadIdx.x >> 6);
  int lane = threadIdx.x & 63;
  const float* xr = x + (size_t)t * Dv;
  float acc[Ev];
#pragma unroll
  for (int e = 0; e < Ev; ++e) acc[e] = 0.f;
#pragma unroll
  for (int j = 0; j < 4; ++j) {
    int dbase = (lane + 64 * j) * 4;
    float4 xv = *(const float4*)(xr + dbase);
    const float* wr = Wg + (size_t)dbase * Ev;
#pragma unroll
    for (int u = 0; u < 4; ++u) {
      float xd = (&xv.x)[u];
#pragma unroll
      for (int e = 0; e < Ev; ++e) acc[e] += xd * wr[u * Ev + e];
    }
  }
#pragma unroll
  for (int off = 32; off > 0; off >>= 1) {
#pragma unroll
    for (int e = 0; e < Ev; ++e) acc[e] += __shfl_xor(acc[e], off, 64);
  }
  if (lane == 0) {
    float mx = acc[0]; int i1 = 0;
#pragma unroll
    for (int e = 1; e < Ev; ++e) { if (acc[e] > mx) { mx = acc[e]; i1 = e; } }
    float ge[Ev]; float se = 0.f;
#pragma unroll
    for (int e = 0; e < Ev; ++e) { ge[e] = expf(acc[e] - mx); se += ge[e]; }
    float mx2 = -INFINITY; int i2 = 0; bool have = false;
#pragma unroll
    for (int e = 0; e < Ev; ++e) {
      if (e == i1) continue;
      if (!have || acc[e] > mx2) { mx2 = acc[e]; i2 = e; have = true; }
    }
    float g1 = 0.f, g2 = 0.f;
#pragma unroll
    for (int e = 0; e < Ev; ++e) { if (e == i1) g1 = ge[e]; if (e == i2) g2 = ge[e]; }
    g1 /= se; g2 /= se;
    float denom = g1 + g2 + 1e-9f;
    idx1[t] = i1; idx2[t] = i2;
    w1[t] = g1 / denom; w2[t] = g2 / denom;
  }
}

// ---------- GShard slot assignment scan (single block, wave-parallel prefix) ----------
__global__ void __launch_bounds__(256)
scan_kernel(const int* __restrict__ gidx1, const int* __restrict__ gidx2,
            const float* __restrict__ gw1, const float* __restrict__ gw2,
            int* __restrict__ ci1, int* __restrict__ ci2,
            float* __restrict__ w1k, float* __restrict__ w2k,
            int* __restrict__ n_e, int* __restrict__ base_e) {
  __shared__ short s1[Tt], s2[Tt];
  __shared__ int cnt[2][256][Ev];
  __shared__ int tot[2][Ev];
  __shared__ int sbase[Ev];
  int tid = threadIdx.x;
  for (int i = tid; i < Tt; i += 256) { s1[i] = (short)gidx1[i]; s2[i] = (short)gidx2[i]; }
  __syncthreads();
  int base = tid * 16;
  {
    int l1[Ev], l2[Ev];
#pragma unroll
    for (int e = 0; e < Ev; ++e) { l1[e] = 0; l2[e] = 0; }
    for (int j = 0; j < 16; ++j) {
      int a = s1[base + j], b = s2[base + j];
#pragma unroll
      for (int e = 0; e < Ev; ++e) { l1[e] += (a == e); l2[e] += (b == e); }
    }
#pragma unroll
    for (int e = 0; e < Ev; ++e) { cnt[0][tid][e] = l1[e]; cnt[1][tid][e] = l2[e]; }
  }
  __syncthreads();
  // 16 columns (arr, e); wave w handles columns 4w..4w+3 via shuffle scan
  {
    int wave = tid >> 6, lane = tid & 63;
#pragma unroll
    for (int q = 0; q < 4; ++q) {
      int col = wave * 4 + q;
      int arr = col >> 3, e = col & 7;
      int* cp = &cnt[arr][0][e];
      int v0 = cp[(lane * 4 + 0) * Ev];
      int v1 = cp[(lane * 4 + 1) * Ev];
      int v2 = cp[(lane * 4 + 2) * Ev];
      int v3 = cp[(lane * 4 + 3) * Ev];
      int sum = v0 + v1 + v2 + v3;
      int incl = sum;
#pragma unroll
      for (int off = 1; off < 64; off <<= 1) {
        int tval = __shfl_up(incl, off, 64);
        if (lane >= off) incl += tval;
      }
      int excl = incl - sum;
      cp[(lane * 4 + 0) * Ev] = excl;
      cp[(lane * 4 + 1) * Ev] = excl + v0;
      cp[(lane * 4 + 2) * Ev] = excl + v0 + v1;
      cp[(lane * 4 + 3) * Ev] = excl + v0 + v1 + v2;
      if (lane == 63) tot[arr][e] = incl;
    }
  }
  __syncthreads();
  if (tid == 0) {
    int b = 0;
#pragma unroll
    for (int e = 0; e < Ev; ++e) {
      int ne = tot[0][e] + tot[1][e];
      ne = ne < CAP ? ne : CAP;
      sbase[e] = b;
      n_e[e] = ne; base_e[e] = b;
      b += ne;
    }
  }
  __syncthreads();
  int r1[Ev], r2[Ev];
#pragma unroll
  for (int e = 0; e < Ev; ++e) {
    r1[e] = cnt[0][tid][e];
    r2[e] = cnt[1][tid][e] + tot[0][e];
  }
  for (int j = 0; j < 16; ++j) {
    int tk = base + j;
    int e1 = s1[tk], e2 = s2[tk];
    int p1 = 0, p2 = 0;
#pragma unroll
    for (int e = 0; e < Ev; ++e) {
      if (e == e1) { p1 = r1[e]; r1[e]++; }
      if (e == e2) { p2 = r2[e]; r2[e]++; }
    }
    bool k1 = p1 < CAP, k2 = p2 < CAP;
    ci1[tk] = k1 ? (sbase[e1] + p1) : -1;
    ci2[tk] = k2 ? (sbase[e2] + p2) : -1;
    w1k[tk] = k1 ? gw1[tk] : 0.f;
    w2k[tk] = k2 ? gw2[tk] : 0.f;
  }
}

// ---------- dispatch ----------
__global__ void __launch_bounds__(256)
dispatch_kernel(const float* __restrict__ x,
                const int* __restrict__ ci1, const int* __restrict__ ci2,
                unsigned short* __restrict__ Xe) {
  int t = blockIdx.x, tid = threadIdx.x;
  float4 xv = *(const float4*)(x + (size_t)t * Dv + tid * 4);
  ushort4 bv;
  bv.x = f2bf(xv.x); bv.y = f2bf(xv.y); bv.z = f2bf(xv.z); bv.w = f2bf(xv.w);
  int c1 = ci1[t], c2 = ci2[t];
  if (c1 >= 0) *(ushort4*)(Xe + (size_t)c1 * Dv + tid * 4) = bv;
  if (c2 >= 0) *(ushort4*)(Xe + (size_t)c2 * Dv + tid * 4) = bv;
}

// ---------- bf16 GEMM, BK=64, XOR-swizzled LDS, compact A rows, BN-templated ----------
// A: compact [NROW+RPAD, K]; Bt: [E, N, K]; grid (x=expert, y=N/BN, z=m-tiles)
// MODE 0: out bf16 = gelu(acc+bias); MODE 1: out bf16 = acc+bias
template <int MODE, int BN>
__global__ void __launch_bounds__(256, 2)
gemm_kernel(const unsigned short* __restrict__ A,
            const unsigned short* __restrict__ Bt,
            const float* __restrict__ bias,
            unsigned short* __restrict__ Out,
            const int* __restrict__ n_e, const int* __restrict__ base_e,
            int N, int K) {
  constexpr int NI = BN / 32;           // n-frags per wave (BN=128 -> 4, BN=64 -> 2)
  int e = blockIdx.x;
  int m0 = blockIdx.z * 128;
  int ne = n_e[e];
  if (m0 >= ne) return;
  int rbase = base_e[e];
  int n0 = blockIdx.y * BN;
  A += ((size_t)(rbase + m0)) * K;
  Bt += (size_t)e * N * K + (size_t)n0 * K;
  bias += (size_t)e * N;

  __shared__ unsigned short As[128 * 64];
  __shared__ unsigned short Bs[BN * 64];
  int tid = threadIdx.x;
  int wave = tid >> 6, lane = tid & 63;
  int wm = (wave & 1) * 64, wn = (wave >> 1) * (BN / 2);
  int quad = lane >> 4, lr = lane & 15;
  int sw = lr & 7;
  f32x4 acc[4][NI];
#pragma unroll
  for (int i = 0; i < 4; ++i)
#pragma unroll
    for (int j = 0; j < NI; ++j)
#pragma unroll
      for (int r = 0; r < 4; ++r) acc[i][j][r] = 0.f;

  int r_st = tid >> 3;   // 0..31
  int g_st = tid & 7;
  int gsrc = g_st ^ (r_st & 7);
  const unsigned short* gA = A + (size_t)r_st * K + gsrc * 8;
  const unsigned short* gB = Bt + (size_t)r_st * K + gsrc * 8;
  unsigned short* lA = &As[tid * 8];
  unsigned short* lB = &Bs[tid * 8];

  for (int k0 = 0; k0 < K; k0 += 64) {
    __syncthreads();
#pragma unroll
    for (int s = 0; s < 4; ++s)
      gload_lds16(gA + (size_t)(s * 32) * K + k0, lA + s * 2048);
#pragma unroll
    for (int s = 0; s < BN / 32; ++s)
      gload_lds16(gB + (size_t)(s * 32) * K + k0, lB + s * 2048);
    __syncthreads();
#pragma unroll
    for (int h = 0; h < 2; ++h) {
      bf16x8 af[4], bfr[NI];
#pragma unroll
      for (int mi = 0; mi < 4; ++mi) {
        int row = wm + mi * 16 + lr;
        int c = (h * 4 + quad) ^ sw;
        af[mi] = *(const bf16x8*)&As[row * 64 + c * 8];
      }
#pragma unroll
      for (int ni = 0; ni < NI; ++ni) {
        int row = wn + ni * 16 + lr;
        int c = (h * 4 + quad) ^ sw;
        bfr[ni] = *(const bf16x8*)&Bs[row * 64 + c * 8];
      }
#pragma unroll
      for (int mi = 0; mi < 4; ++mi)
#pragma unroll
        for (int ni = 0; ni < NI; ++ni)
          acc[mi][ni] = __builtin_amdgcn_mfma_f32_16x16x32_bf16(af[mi], bfr[ni], acc[mi][ni], 0, 0, 0);
    }
  }

#pragma unroll
  for (int ni = 0; ni < NI; ++ni) {
    int col = n0 + wn + ni * 16 + lr;
    float bv = bias[col];
#pragma unroll
    for (int mi = 0; mi < 4; ++mi) {
#pragma unroll
      for (int r = 0; r < 4; ++r) {
        int rowl = m0 + wm + mi * 16 + quad * 4 + r;
        if (rowl < ne) {
          size_t grow = (size_t)(rbase + rowl);
          float v = acc[mi][ni][r] + bv;
          if (MODE == 0)
            v = 0.5f * v * (1.0f + erff(v * 0.70710678118654752f));
          Out[grow * N + col] = f2bf(v);
        }
      }
    }
  }
}

// ---------- combine (ye bf16) ----------
__global__ void __launch_bounds__(256)
combine_kernel(const unsigned short* __restrict__ ye,   // [NROW][Dv] bf16
               const int* __restrict__ ci1, const int* __restrict__ ci2,
               const float* __restrict__ w1k, const float* __restrict__ w2k,
               float* __restrict__ out) {
  int t = blockIdx.x, tid = threadIdx.x;
  int c1 = ci1[t], c2 = ci2[t];
  float a1 = w1k[t], a2 = w2k[t];
  float4 o = make_float4(0.f, 0.f, 0.f, 0.f);
  if (c1 >= 0) {
    ushort4 y = *(const ushort4*)(ye + (size_t)c1 * Dv + tid * 4);
    o.x += a1 * bf2f(y.x); o.y += a1 * bf2f(y.y);
    o.z += a1 * bf2f(y.z); o.w += a1 * bf2f(y.w);
  }
  if (c2 >= 0) {
    ushort4 y = *(const ushort4*)(ye + (size_t)c2 * Dv + tid * 4);
    o.x += a2 * bf2f(y.x); o.y += a2 * bf2f(y.y);
    o.z += a2 * bf2f(y.z); o.w += a2 * bf2f(y.w);
  }
  *(float4*)(out + (size_t)t * Dv + tid * 4) = o;
}

extern "C" void kernel_launch(void* const* d_in, const int* in_sizes, int n_in,
                              void* d_out, int out_size, void* d_ws, size_t ws_size,
                              hipStream_t stream) {
  const float* x  = (const float*)d_in[0];
  const float* Wg = (const float*)d_in[1];
  const float* W1 = (const float*)d_in[2];
  const float* b1 = (const float*)d_in[3];
  const float* W2 = (const float*)d_in[4];
  const float* b2 = (const float*)d_in[5];
  float* out = (float*)d_out;

  char* p = (char*)d_ws;
  size_t off = 0;
  auto alloc = [&](size_t bytes) {
    void* q = p + off;
    off += (bytes + 255) & ~(size_t)255;
    return q;
  };
  unsigned short* Wt1 = (unsigned short*)alloc((size_t)Ev * Fv * Dv * 2);       // 64MB (ye aliases after fc1)
  unsigned short* Wt2 = (unsigned short*)alloc((size_t)Ev * Dv * Fv * 2);       // 64MB
  unsigned short* Xe  = (unsigned short*)alloc((size_t)(NROW + RPAD) * Dv * 2); // 17MB compact
  unsigned short* h   = (unsigned short*)alloc((size_t)(NROW + RPAD) * Fv * 2); // 68MB compact
  int*   idx1 = (int*)alloc(Tt * 4);
  int*   idx2 = (int*)alloc(Tt * 4);
  int*   ci1  = (int*)alloc(Tt * 4);
  int*   ci2  = (int*)alloc(Tt * 4);
  float* w1   = (float*)alloc(Tt * 4);
  float* w2   = (float*)alloc(Tt * 4);
  float* w1k  = (float*)alloc(Tt * 4);
  float* w2k  = (float*)alloc(Tt * 4);
  int*   n_e  = (int*)alloc(Ev * 4);
  int*   base = (int*)alloc(Ev * 4);
  unsigned short* ye = Wt1;  // [NROW][Dv] bf16 = 16MB, aliases Wt1 (dead after fc1)

  // 1) fused transposes + gating
  pre_kernel<<<17408, 256, 0, stream>>>(W1, Wt1, W2, Wt2, x, Wg, idx1, idx2, w1, w2);
  // 2) slot assignment -> compact indices
  scan_kernel<<<1, 256, 0, stream>>>(idx1, idx2, w1, w2, ci1, ci2, w1k, w2k, n_e, base);
  // 3) dispatch to compact Xe
  dispatch_kernel<<<Tt, 256, 0, stream>>>(x, ci1, ci2, Xe);
  // 4) fc1: h = gelu(Xe @ W1 + b1)  [N=F, K=D], 128x128 tiles
  gemm_kernel<0, 128><<<dim3(Ev, Fv / 128, CAP / 128), 256, 0, stream>>>(
      Xe, Wt1, b1, h, n_e, base, Fv, Dv);
  // 5) fc2: ye = h @ W2 + b2  [N=D, K=F], 128x64 tiles for 2x block count
  gemm_kernel<1, 64><<<dim3(Ev, Dv / 64, CAP / 128), 256, 0, stream>>>(
      h, Wt2, b2, ye, n_e, base, Dv, Fv);
  // 6) combine
  combine_kernel<<<Tt, 256, 0, stream>>>(ye, ci1, ci2, w1k, w2k, out);
}